// Round 8
// baseline (458.511 us; speedup 1.0000x reference)
//
#include <hip/hip_runtime.h>
#include <cstdint>

// Problem constants (static per reference)
#define T_TOK 16384     // B*S
#define HD    1024      // H
#define NE    8         // experts
#define CAP   2560      // ceil(1.25*T/E)
#define NCHUNK (T_TOK / 64)   // 256

typedef __attribute__((ext_vector_type(4))) float f32x4;
typedef __attribute__((ext_vector_type(8))) short bf16x8;   // 8 bf16 = 4 VGPRs

__device__ __forceinline__ unsigned short f2bf(float f) {
    union { float f; unsigned u; } x{f};
    unsigned r = x.u + 0x7FFF + ((x.u >> 16) & 1);   // RNE
    return (unsigned short)(r >> 16);
}

__device__ __forceinline__ void gload_lds16(const unsigned short* g, unsigned short* l) {
    __builtin_amdgcn_global_load_lds(
        (const __attribute__((address_space(1))) void*)g,
        (__attribute__((address_space(3))) void*)l, 16, 0, 0);
}

// one BK=64 tile of MFMA work (two K=32 halves), XOR-swizzled ds_reads
__device__ __forceinline__ void mfma_tile(
    const unsigned short (&A)[128][64],
    const unsigned short (&B)[128][64],
    f32x4 (&acc)[4][4], int wm, int wn, int fr, int kg)
{
    #pragma unroll
    for (int kk = 0; kk < 2; ++kk) {
        bf16x8 af[4], bfr[4];
        #pragma unroll
        for (int i2 = 0; i2 < 4; ++i2) {
            int R = wm * 64 + i2 * 16 + fr;
            af[i2] = *(const bf16x8*)&A[R][((kk * 4 + kg) ^ (R & 7)) * 8];
        }
        #pragma unroll
        for (int j2 = 0; j2 < 4; ++j2) {
            int R = wn * 64 + j2 * 16 + fr;
            bfr[j2] = *(const bf16x8*)&B[R][((kk * 4 + kg) ^ (R & 7)) * 8];
        }
        #pragma unroll
        for (int i2 = 0; i2 < 4; ++i2)
            #pragma unroll
            for (int j2 = 0; j2 < 4; ++j2)
                acc[i2][j2] = __builtin_amdgcn_mfma_f32_16x16x32_bf16(
                    af[i2], bfr[j2], acc[i2][j2], 0, 0, 0);
    }
}

// ---------------------------------------------------------------------------
// bf16 MFMA GEMM: C[M,N] = op(A[M,K] @ Bt[N,K]^T + bias[N])
// 128x128 tile, BK=64, 4 waves (2x2 of 64x64), 16x16x32 MFMA.
// - XCD-aware bijective block swizzle (R6: FETCH 206->70MB).
// - 128B LDS rows + 16B-chunk XOR swizzle (R6: 0 bank conflicts).
// - R8: double-buffer + COUNTED vmcnt. Per iter: stage(t+1) ->
//   s_waitcnt vmcnt(8) (waits tile t only; t+1's 8 loads stay in flight
//   across the whole MFMA phase) -> s_barrier -> MFMA -> s_barrier.
//   Never vmcnt(0) in the main loop (T4); last tile peeled with vmcnt(0).
//   Race proof: vmcnt(8)+barrier => all waves' tile-t loads landed before
//   any ds_read; post-MFMA barrier => all ds_reads retired (lgkmcnt forced
//   by MFMA operand use) before next iter's stage overwrites that buffer.
// ---------------------------------------------------------------------------
template<bool GATHER, bool RELU, bool ROWSCALE, bool SCATTER, bool OUTBF16>
__global__ __launch_bounds__(256)
void gemm_bf16_k(const unsigned short* __restrict__ A,
                 const unsigned short* __restrict__ Bt,
                 const float* __restrict__ bias,
                 void* __restrict__ Cv,
                 int M, int N, int K,
                 const int* __restrict__ idxTab,
                 const float* __restrict__ rs,
                 long aB, long bB, long biasB, long tabB, long cB)
{
    // ---- XCD-aware remap: XCD c gets contiguous logical chunk ----
    const int nx = gridDim.x, ny = gridDim.y;
    long nwg = (long)nx * ny * gridDim.z;
    long flat = blockIdx.x + (long)nx * (blockIdx.y + (long)ny * blockIdx.z);
    long cpx = nwg >> 3;                       // nwg % 8 == 0 by construction
    long swz = (flat & 7) * cpx + (flat >> 3);
    const int bx = (int)(swz % nx);
    const int by = (int)((swz / nx) % ny);
    const int bz = (int)(swz / ((long)nx * ny));

    A  += (long)bz * aB;
    Bt += (long)bz * bB;
    const float* bptr = bias + (long)bz * biasB;
    const int* tab = idxTab ? idxTab + (long)bz * tabB : nullptr;
    float*          Cf = (float*)Cv + (long)bz * cB;
    unsigned short* Cb = (unsigned short*)Cv + (long)bz * cB;

    __shared__ unsigned short As[2][128][64];   // 2 x 16 KB
    __shared__ unsigned short Bs[2][128][64];   // 2 x 16 KB  (total 64 KB)

    const int tid  = threadIdx.x;
    const int wv   = tid >> 6;
    const int lane = tid & 63;
    const int m0 = by * 128, n0 = bx * 128;

    // staging: per wave 4 issues for A + 4 for B; issue = 8 rows x 128 B.
    // lane l -> LDS row base+(l>>3), 16B chunk (l&7). Source chunk is
    // pre-swizzled: c_src = (l&7) ^ (row&7).
    const int srow = lane >> 3;
    const int schk = lane & 7;

    const unsigned short* aSrc[4];
    const unsigned short* bSrc[4];
    #pragma unroll
    for (int i = 0; i < 4; ++i) {
        int lrow = wv * 32 + i * 8 + srow;          // LDS row 0..127
        int scol = ((schk ^ (lrow & 7)) * 8);       // swizzled col (elems)
        long sr;
        if (GATHER) { int tr = tab[m0 + lrow]; sr = tr < 0 ? 0 : tr; }
        else        sr = m0 + lrow;
        aSrc[i] = A + sr * (long)K + scol;
        bSrc[i] = Bt + (long)(n0 + lrow) * K + scol;
    }

    f32x4 acc[4][4] = {};
    const int wm = wv >> 1, wn = wv & 1;
    const int fr = lane & 15, kg = lane >> 4;
    const int NT = K >> 6;                      // K / 64

    // prologue: stage tile 0 into buffer 0 (8 loads/wave in flight)
    #pragma unroll
    for (int i = 0; i < 4; ++i) {
        gload_lds16(aSrc[i], &As[0][wv * 32 + i * 8][0]);
        gload_lds16(bSrc[i], &Bs[0][wv * 32 + i * 8][0]);
    }

    int cur = 0;
    for (int t = 0; t < NT - 1; ++t) {
        const int k0 = (t + 1) << 6;            // prefetch next tile
        #pragma unroll
        for (int i = 0; i < 4; ++i) {
            gload_lds16(aSrc[i] + k0, &As[cur ^ 1][wv * 32 + i * 8][0]);
            gload_lds16(bSrc[i] + k0, &Bs[cur ^ 1][wv * 32 + i * 8][0]);
        }
        // wait for tile t's 8 loads only; t+1's ride through the MFMA phase
        asm volatile("s_waitcnt vmcnt(8)" ::: "memory");
        __builtin_amdgcn_s_barrier();
        mfma_tile(As[cur], Bs[cur], acc, wm, wn, fr, kg);
        __builtin_amdgcn_s_barrier();           // all reads of buf done
        cur ^= 1;
    }
    asm volatile("s_waitcnt vmcnt(0)" ::: "memory");   // last tile landed
    __builtin_amdgcn_s_barrier();
    mfma_tile(As[cur], Bs[cur], acc, wm, wn, fr, kg);

    // epilogue: C/D layout col = lane&15, row = (lane>>4)*4 + r
    const int colL = lane & 15, rgrp = (lane >> 4) * 4;
    #pragma unroll
    for (int i2 = 0; i2 < 4; ++i2) {
        #pragma unroll
        for (int r = 0; r < 4; ++r) {
            int gm = m0 + wm * 64 + i2 * 16 + rgrp + r;
            int token = gm; float sc = 1.0f;
            if (SCATTER) {
                token = tab[gm];
                if (token < 0) continue;
                sc = rs[token];
            } else if (ROWSCALE) {
                sc = rs[gm];
            }
            #pragma unroll
            for (int j2 = 0; j2 < 4; ++j2) {
                int gn = n0 + wn * 64 + j2 * 16 + colL;
                float v = acc[i2][j2][r] + bptr[gn];
                if (RELU) v = fmaxf(v, 0.0f);
                if (SCATTER) {
                    Cf[(long)token * N + gn] += v * sc;     // unique writer
                } else {
                    if (ROWSCALE) v *= sc;
                    if (OUTBF16) Cb[(long)gm * N + gn] = f2bf(v);
                    else         Cf[(long)gm * N + gn] = v;
                }
            }
        }
    }
}

// ---------------------------------------------------------------------------
// f32 -> bf16 cast (vectorized)
// ---------------------------------------------------------------------------
__global__ __launch_bounds__(256)
void cast_bf16_k(const float* __restrict__ in, unsigned short* __restrict__ out,
                 long n4)
{
    long i = (long)blockIdx.x * 256 + threadIdx.x;
    long stride = (long)gridDim.x * 256;
    for (; i < n4; i += stride) {
        float4 v = ((const float4*)in)[i];
        ushort4 o;
        o.x = f2bf(v.x); o.y = f2bf(v.y); o.z = f2bf(v.z); o.w = f2bf(v.w);
        ((ushort4*)out)[i] = o;
    }
}

// ---------------------------------------------------------------------------
// Transpose + cast: W[K][N] f32 -> Wt[N][K] bf16, 64x64 LDS tiles. z batched.
// ---------------------------------------------------------------------------
__global__ __launch_bounds__(256)
void transpose_cast_k(const float* __restrict__ W, unsigned short* __restrict__ Wt,
                      int K, int N, long wB, long wtB)
{
    const int z = blockIdx.z;
    W  += (long)z * wB;
    Wt += (long)z * wtB;
    __shared__ float tile[64][65];
    const int k0 = blockIdx.x * 64, n0 = blockIdx.y * 64;
    const int c = threadIdx.x & 63, r4 = threadIdx.x >> 6;
    #pragma unroll 4
    for (int it = 0; it < 16; ++it) {
        int row = it * 4 + r4;
        tile[row][c] = W[(long)(k0 + row) * N + n0 + c];
    }
    __syncthreads();
    #pragma unroll 4
    for (int it = 0; it < 16; ++it) {
        int nrow = it * 4 + r4;
        Wt[(long)(n0 + nrow) * K + k0 + c] = f2bf(tile[c][nrow]);
    }
}

// ---------------------------------------------------------------------------
// Wsmall: Wg'[H][8] = W_in @ W_gate, Wc'[H][2] = W_in @ W_coef  (f32)
// ---------------------------------------------------------------------------
__global__ __launch_bounds__(256)
void wsmall_k(const float* __restrict__ W_in, const float* __restrict__ W_gate,
              const float* __restrict__ W_coef,
              float* __restrict__ wgp, float* __restrict__ wcp)
{
    const int r = blockIdx.x * 4 + (threadIdx.x >> 6);
    const int lane = threadIdx.x & 63;
    float s[10] = {};
    for (int k = lane; k < HD; k += 64) {
        float a = W_in[(long)r * HD + k];
        const float4* g = (const float4*)(W_gate + (long)k * 8);
        float4 g0 = g[0], g1 = g[1];
        s[0] += a * g0.x; s[1] += a * g0.y; s[2] += a * g0.z; s[3] += a * g0.w;
        s[4] += a * g1.x; s[5] += a * g1.y; s[6] += a * g1.z; s[7] += a * g1.w;
        float2 cv = *(const float2*)(W_coef + (long)k * 2);
        s[8] += a * cv.x; s[9] += a * cv.y;
    }
    #pragma unroll
    for (int off = 32; off > 0; off >>= 1)
        #pragma unroll
        for (int e = 0; e < 10; ++e) s[e] += __shfl_xor(s[e], off);
    if (lane == 0) {
        #pragma unroll
        for (int e = 0; e < 8; ++e) wgp[(long)r * 8 + e] = s[e];
        wcp[(long)r * 2 + 0] = s[8];
        wcp[(long)r * 2 + 1] = s[9];
    }
}

// bg[8] = b_in @ W_gate ; bc[2] = b_in @ W_coef + b_coef
__global__ void gbias_k(const float* __restrict__ b_in, const float* __restrict__ W_gate,
                        const float* __restrict__ W_coef, const float* __restrict__ b_coef,
                        float* __restrict__ bg, float* __restrict__ bc)
{
    const int lane = threadIdx.x;  // 64
    float s[10] = {};
    for (int k = lane; k < HD; k += 64) {
        float a = b_in[k];
        const float4* g = (const float4*)(W_gate + (long)k * 8);
        float4 g0 = g[0], g1 = g[1];
        s[0] += a * g0.x; s[1] += a * g0.y; s[2] += a * g0.z; s[3] += a * g0.w;
        s[4] += a * g1.x; s[5] += a * g1.y; s[6] += a * g1.z; s[7] += a * g1.w;
        float2 cv = *(const float2*)(W_coef + (long)k * 2);
        s[8] += a * cv.x; s[9] += a * cv.y;
    }
    #pragma unroll
    for (int off = 32; off > 0; off >>= 1)
        #pragma unroll
        for (int e = 0; e < 10; ++e) s[e] += __shfl_xor(s[e], off);
    if (lane == 0) {
        #pragma unroll
        for (int e = 0; e < 8; ++e) bg[e] = s[e];
        bc[0] = s[8] + b_coef[0];
        bc[1] = s[9] + b_coef[1];
    }
}

// ---------------------------------------------------------------------------
// Gating from x with fused weights (one wave per token).
// ---------------------------------------------------------------------------
__global__ __launch_bounds__(256)
void gating_k(const float* __restrict__ x,
              const float* __restrict__ Wg,   // [H,8] fused
              const float* __restrict__ Wc,   // [H,2] fused
              const float* __restrict__ bg,   // [8]
              const float* __restrict__ bc,   // [2]
              int* __restrict__ eidx,
              float* __restrict__ gval,
              float* __restrict__ coef0,
              float* __restrict__ coef1)
{
    const int tok = (blockIdx.x * 256 + threadIdx.x) >> 6;
    const int lane = threadIdx.x & 63;
    const float* row = x + (long)tok * HD;

    float acc[8] = {};
    float c0 = 0.f, c1 = 0.f;
    for (int i = 0; i < HD / 64; ++i) {
        int k = i * 64 + lane;
        float tv = row[k];
        const float4* wg = (const float4*)(Wg + (long)k * 8);
        float4 w0 = wg[0], w1 = wg[1];
        acc[0] = fmaf(tv, w0.x, acc[0]); acc[1] = fmaf(tv, w0.y, acc[1]);
        acc[2] = fmaf(tv, w0.z, acc[2]); acc[3] = fmaf(tv, w0.w, acc[3]);
        acc[4] = fmaf(tv, w1.x, acc[4]); acc[5] = fmaf(tv, w1.y, acc[5]);
        acc[6] = fmaf(tv, w1.z, acc[6]); acc[7] = fmaf(tv, w1.w, acc[7]);
        float2 wcv = *(const float2*)(Wc + (long)k * 2);
        c0 = fmaf(tv, wcv.x, c0);
        c1 = fmaf(tv, wcv.y, c1);
    }
    #pragma unroll
    for (int off = 32; off > 0; off >>= 1) {
        #pragma unroll
        for (int e = 0; e < 8; ++e) acc[e] += __shfl_xor(acc[e], off);
        c0 += __shfl_xor(c0, off);
        c1 += __shfl_xor(c1, off);
    }
    if (lane == 0) {
        #pragma unroll
        for (int e = 0; e < 8; ++e) acc[e] += bg[e];
        float m = acc[0]; int best = 0;
        #pragma unroll
        for (int e = 1; e < 8; ++e) if (acc[e] > m) { m = acc[e]; best = e; }
        float s = 0.f;
        #pragma unroll
        for (int e = 0; e < 8; ++e) s += expf(acc[e] - m);
        eidx[tok] = best;
        gval[tok] = 1.0f / s;
        float l0 = c0 + bc[0], l1 = c1 + bc[1];
        float mm = fmaxf(l0, l1);
        float e0 = expf(l0 - mm), e1 = expf(l1 - mm);
        float inv = 1.0f / (e0 + e1);
        coef0[tok] = e0 * inv;
        coef1[tok] = e1 * inv;
    }
}

// ---------------------------------------------------------------------------
// Parallel capacity scan, 3 phases (integer-exact, verified round 5).
// ---------------------------------------------------------------------------
__global__ void scan_hist_k(const int* __restrict__ eidx,
                            int* __restrict__ counts,
                            int* __restrict__ idxTab)
{
    const int b = blockIdx.x;          // chunk id, 0..255
    const int lane = threadIdx.x;      // 64
    for (int j = b * 64 + lane; j < NE * CAP; j += NCHUNK * 64)
        idxTab[j] = -1;
    int e = eidx[b * 64 + lane];
    #pragma unroll
    for (int ex = 0; ex < NE; ++ex) {
        unsigned long long msk = __ballot(e == ex);
        if (lane == ex) counts[b * NE + ex] = (int)__popcll(msk);
    }
}

__global__ void scan_offsets_k(const int* __restrict__ counts,
                               int* __restrict__ offsets)
{
    const int e = threadIdx.x;         // 64 threads, 8 active
    if (e < NE) {
        int run = 0;
        for (int b = 0; b < NCHUNK; ++b) {
            offsets[b * NE + e] = run;
            run += counts[b * NE + e];
        }
    }
}

__global__ void scan_fill_k(const int* __restrict__ eidx,
                            const float* __restrict__ gval,
                            const float* __restrict__ coef0,
                            const int* __restrict__ offsets,
                            int* __restrict__ idxTab,
                            float* __restrict__ smoe)
{
    const int b = blockIdx.x;
    const int lane = threadIdx.x;
    const int tok = b * 64 + lane;
    int e = eidx[tok];
    unsigned long long below = (lane == 0) ? 0ull : ((~0ull) >> (64 - lane));
    int myrank = 0;
    #pragma unroll
    for (int ex = 0; ex < NE; ++ex) {
        unsigned long long msk = __ballot(e == ex);
        if (e == ex) myrank = (int)__popcll(msk & below) + offsets[b * NE + ex];
    }
    if (myrank < CAP) {
        idxTab[e * CAP + myrank] = tok;
        smoe[tok] = gval[tok] * coef0[tok];
    } else {
        smoe[tok] = 0.0f;
    }
}

// ---------------------------------------------------------------------------
// Workspace plan (lifetime-aliased; ~134.8 MB):
//   slotA [0,32Mi):   W1T then res1 then mixb
//   h     [32,72Mi);  t_b [72,104Mi); W2T [104,120Mi);
//   WinT/Wr1T/Wr2T/WoutT [120..128Mi); small [128Mi..)
//   xb: d_out[0,32Mi);  mix: d_out f32;  out: d_out
// ---------------------------------------------------------------------------
extern "C" void kernel_launch(void* const* d_in, const int* in_sizes, int n_in,
                              void* d_out, int out_size, void* d_ws, size_t ws_size,
                              hipStream_t stream)
{
    const float* x      = (const float*)d_in[0];
    const float* W_in   = (const float*)d_in[1];
    const float* b_in   = (const float*)d_in[2];
    const float* W_gate = (const float*)d_in[3];
    const float* W1     = (const float*)d_in[4];
    const float* b1     = (const float*)d_in[5];
    const float* W2     = (const float*)d_in[6];
    const float* b2     = (const float*)d_in[7];
    const float* Wr1    = (const float*)d_in[8];
    const float* br1    = (const float*)d_in[9];
    const float* Wr2    = (const float*)d_in[10];
    const float* br2    = (const float*)d_in[11];
    const float* W_coef = (const float*)d_in[12];
    const float* b_coef = (const float*)d_in[13];
    const float* W_out  = (const float*)d_in[14];
    const float* b_out  = (const float*)d_in[15];
    float* out = (float*)d_out;

    const size_t MiB = 1024 * 1024;
    char* ws = (char*)d_ws;
    unsigned short* W1T  = (unsigned short*)(ws + 0);          // 16 MiB
    unsigned short* res1 = (unsigned short*)(ws + 0);          // 32 MiB (after FC1)
    unsigned short* mixb = (unsigned short*)(ws + 0);          // 32 MiB (after res-mix)
    unsigned short* h    = (unsigned short*)(ws + 32 * MiB);   // 40 MiB
    unsigned short* t_b  = (unsigned short*)(ws + 72 * MiB);   // 32 MiB
    unsigned short* W2T  = (unsigned short*)(ws + 104 * MiB);  // 16 MiB
    unsigned short* WinT = (unsigned short*)(ws + 120 * MiB);  // 2 MiB
    unsigned short* Wr1T = (unsigned short*)(ws + 122 * MiB);  // 2 MiB
    unsigned short* Wr2T = (unsigned short*)(ws + 124 * MiB);  // 2 MiB
    unsigned short* WoutT= (unsigned short*)(ws + 126 * MiB);  // 2 MiB
    char* sm = ws + 128 * MiB;
    float* wgp  = (float*)(sm);            sm += HD * 8 * 4;
    float* wcp  = (float*)(sm);            sm += HD * 2 * 4;
    float* bg   = (float*)(sm);            sm += 64;
    float* bc   = (float*)(sm);            sm += 64;
    int*   eidx = (int*)(sm);              sm += T_TOK * 4;
    float* gval = (float*)(sm);            sm += T_TOK * 4;
    float* cf0  = (float*)(sm);            sm += T_TOK * 4;
    float* cf1  = (float*)(sm);            sm += T_TOK * 4;
    float* smoe = (float*)(sm);            sm += T_TOK * 4;
    int* idxTab = (int*)(sm);              sm += NE * CAP * 4;
    int* counts = (int*)(sm);              sm += NCHUNK * NE * 4;
    int* offs   = (int*)(sm);              sm += NCHUNK * NE * 4;
    unsigned short* xb = (unsigned short*)d_out;   // 32 MiB, dies before mix
    float* mix = out;                               // f32
    (void)ws_size; (void)in_sizes; (void)n_in; (void)out_size;

    dim3 blk(256);
    dim3 gT(16, 16, 1);
    dim3 gT8(16, 16, 8);
    dim3 gBig(HD / 128, T_TOK / 128, 1);   // 8 x 128 = 1024 blocks (%8==0)
    dim3 gExp(HD / 128, CAP / 128, NE);    // 8 x 20 x 8 = 1280 blocks (%8==0)

    // a. xb = bf16(x)
    cast_bf16_k<<<2048, blk, 0, stream>>>(x, xb, (long)T_TOK * HD / 4);
    // b. weight transposes (bf16 [N][K])
    transpose_cast_k<<<gT,  blk, 0, stream>>>(W_in,  WinT,  HD, HD, 0, 0);
    transpose_cast_k<<<gT,  blk, 0, stream>>>(Wr1,   Wr1T,  HD, HD, 0, 0);
    transpose_cast_k<<<gT,  blk, 0, stream>>>(Wr2,   Wr2T,  HD, HD, 0, 0);
    transpose_cast_k<<<gT,  blk, 0, stream>>>(W_out, WoutT, HD, HD, 0, 0);
    transpose_cast_k<<<gT8, blk, 0, stream>>>(W1, W1T, HD, HD, (long)HD * HD, (long)HD * HD);
    transpose_cast_k<<<gT8, blk, 0, stream>>>(W2, W2T, HD, HD, (long)HD * HD, (long)HD * HD);
    // c. fused gating weights (f32)
    wsmall_k<<<HD / 4, blk, 0, stream>>>(W_in, W_gate, W_coef, wgp, wcp);
    gbias_k<<<1, 64, 0, stream>>>(b_in, W_gate, W_coef, b_coef, bg, bc);
    // d. gating from x (f32 path for discrete routing)
    gating_k<<<T_TOK / 4, blk, 0, stream>>>(x, wgp, wcp, bg, bc, eidx, gval, cf0, cf1);
    // e. parallel capacity scan
    scan_hist_k<<<NCHUNK, 64, 0, stream>>>(eidx, counts, idxTab);
    scan_offsets_k<<<1, 64, 0, stream>>>(counts, offs);
    scan_fill_k<<<NCHUNK, 64, 0, stream>>>(eidx, gval, cf0, offs, idxTab, smoe);
    // f. t_b = bf16(xb @ W_in + b_in)
    gemm_bf16_k<false, false, false, false, true><<<gBig, blk, 0, stream>>>(
        xb, WinT, b_in, t_b, T_TOK, HD, HD, nullptr, nullptr, 0, 0, 0, 0, 0);
    // h. h[e] = relu(gather(t_b) @ W1[e] + b1[e])   bf16 out
    gemm_bf16_k<true, true, false, false, true><<<gExp, blk, 0, stream>>>(
        t_b, W1T, b1, h, CAP, HD, HD, idxTab, nullptr,
        0, (long)HD * HD, HD, CAP, (long)CAP * HD);
    // i. res1 = relu(t_b @ Wr1 + br1)   bf16 out (overlays W1T slot)
    gemm_bf16_k<false, true, false, false, true><<<gBig, blk, 0, stream>>>(
        t_b, Wr1T, br1, res1, T_TOK, HD, HD, nullptr, nullptr, 0, 0, 0, 0, 0);
    // j. mix = (res1 @ Wr2 + br2) * cf1[row]   f32 -> d_out
    gemm_bf16_k<false, false, true, false, false><<<gBig, blk, 0, stream>>>(
        res1, Wr2T, br2, mix, T_TOK, HD, HD, nullptr, cf1, 0, 0, 0, 0, 0);
    // k. mix[tok] += (h[e] @ W2[e] + b2[e]) * smoe[tok]   f32 RMW
    gemm_bf16_k<false, false, false, true, false><<<gExp, blk, 0, stream>>>(
        h, W2T, b2, mix, CAP, HD, HD, idxTab, smoe,
        (long)CAP * HD, (long)HD * HD, HD, CAP, 0);
    // l. mixb = bf16(mix)
    cast_bf16_k<<<2048, blk, 0, stream>>>(mix, mixb, (long)T_TOK * HD / 4);
    // m. out = mixb @ W_out + b_out   f32 -> d_out
    gemm_bf16_k<false, false, false, false, false><<<gBig, blk, 0, stream>>>(
        mixb, WoutT, b_out, out, T_TOK, HD, HD, nullptr, nullptr, 0, 0, 0, 0, 0);
}

// Round 9
// 418.774 us; speedup vs baseline: 1.0949x; 1.0949x over previous
//
#include <hip/hip_runtime.h>
#include <cstdint>

// Problem constants (static per reference)
#define T_TOK 16384     // B*S
#define HD    1024      // H
#define NE    8         // experts
#define CAP   2560      // ceil(1.25*T/E)
#define NCHUNK (T_TOK / 64)   // 256

typedef __attribute__((ext_vector_type(4))) float f32x4;
typedef __attribute__((ext_vector_type(8))) short bf16x8;   // 8 bf16 = 4 VGPRs

__device__ __forceinline__ unsigned short f2bf(float f) {
    union { float f; unsigned u; } x{f};
    unsigned r = x.u + 0x7FFF + ((x.u >> 16) & 1);   // RNE
    return (unsigned short)(r >> 16);
}

__device__ __forceinline__ void gload_lds16(const unsigned short* g, unsigned short* l) {
    __builtin_amdgcn_global_load_lds(
        (const __attribute__((address_space(1))) void*)g,
        (__attribute__((address_space(3))) void*)l, 16, 0, 0);
}

// ---------------------------------------------------------------------------
// bf16 MFMA GEMM: C[M,N] = op(A[M,K] @ Bt[N,K]^T + bias[N])
// R9: 256x128 tile, BK=64, 8 waves (4m x 2n of 64x64), 16x16x32 MFMA,
// SINGLE-buffer 2-barrier loop (R6 structure — best measured; R7/R8 dbuf
// variants regressed via occupancy loss). 32 MFMA per wave per barrier-pair
// (2x R6) amortizes the stage+drain stall.
// - XCD-aware bijective block swizzle (R6: FETCH 206->70MB).
// - 128B LDS rows + 16B-chunk XOR swizzle on global-source + ds_read,
//   linear gload_lds dest (R6: 0 bank conflicts).
// ---------------------------------------------------------------------------
template<bool GATHER, bool RELU, bool ROWSCALE, bool SCATTER, bool OUTBF16>
__global__ __launch_bounds__(512)
void gemm_bf16_k(const unsigned short* __restrict__ A,
                 const unsigned short* __restrict__ Bt,
                 const float* __restrict__ bias,
                 void* __restrict__ Cv,
                 int M, int N, int K,
                 const int* __restrict__ idxTab,
                 const float* __restrict__ rs,
                 long aB, long bB, long biasB, long tabB, long cB)
{
    // ---- XCD-aware remap: XCD c gets contiguous logical chunk ----
    const int nx = gridDim.x, ny = gridDim.y;
    long nwg = (long)nx * ny * gridDim.z;
    long flat = blockIdx.x + (long)nx * (blockIdx.y + (long)ny * blockIdx.z);
    long cpx = nwg >> 3;                       // nwg % 8 == 0 by construction
    long swz = (flat & 7) * cpx + (flat >> 3);
    const int bx = (int)(swz % nx);
    const int by = (int)((swz / nx) % ny);
    const int bz = (int)(swz / ((long)nx * ny));

    A  += (long)bz * aB;
    Bt += (long)bz * bB;
    const float* bptr = bias + (long)bz * biasB;
    const int* tab = idxTab ? idxTab + (long)bz * tabB : nullptr;
    float*          Cf = (float*)Cv + (long)bz * cB;
    unsigned short* Cb = (unsigned short*)Cv + (long)bz * cB;

    __shared__ unsigned short As[256][64];   // 32 KB, row = m
    __shared__ unsigned short Bs[128][64];   // 16 KB, row = n  (48 KB total)

    const int tid  = threadIdx.x;
    const int wv   = tid >> 6;               // 0..7
    const int lane = tid & 63;
    const int m0 = by * 256, n0 = bx * 128;

    // staging: issue = 8 rows x 128 B = 1024 B = 64 lanes x 16 B.
    // lane l -> row +(l>>3), 16B chunk (l&7); source chunk pre-swizzled.
    const int srow = lane >> 3;
    const int schk = lane & 7;

    const unsigned short* aSrc[4];           // wave stages A rows wv*32..+31
    const unsigned short* bSrc[2];           // wave stages B rows wv*16..+15
    #pragma unroll
    for (int i = 0; i < 4; ++i) {
        int lrow = wv * 32 + i * 8 + srow;          // 0..255
        int scol = ((schk ^ (lrow & 7)) * 8);       // swizzled col (elems)
        long sr;
        if (GATHER) { int tr = tab[m0 + lrow]; sr = tr < 0 ? 0 : tr; }
        else        sr = m0 + lrow;
        aSrc[i] = A + sr * (long)K + scol;
    }
    #pragma unroll
    for (int i = 0; i < 2; ++i) {
        int lrow = wv * 16 + i * 8 + srow;          // 0..127
        int scol = ((schk ^ (lrow & 7)) * 8);
        bSrc[i] = Bt + (long)(n0 + lrow) * K + scol;
    }

    f32x4 acc[4][4] = {};
    const int wm = wv >> 1, wn = wv & 1;     // 4 x 2 wave grid
    const int fr = lane & 15, kg = lane >> 4;

    for (int k0 = 0; k0 < K; k0 += 64) {
        __syncthreads();                     // prev tile fully consumed
        #pragma unroll
        for (int i = 0; i < 4; ++i)
            gload_lds16(aSrc[i] + k0, &As[wv * 32 + i * 8][0]);
        #pragma unroll
        for (int i = 0; i < 2; ++i)
            gload_lds16(bSrc[i] + k0, &Bs[wv * 16 + i * 8][0]);
        __syncthreads();                     // vmcnt(0) drained here

        #pragma unroll
        for (int kk = 0; kk < 2; ++kk) {     // two K=32 halves of BK=64
            bf16x8 af[4], bfr[4];
            #pragma unroll
            for (int i2 = 0; i2 < 4; ++i2) {
                int R = wm * 64 + i2 * 16 + fr;
                af[i2] = *(const bf16x8*)&As[R][((kk * 4 + kg) ^ (R & 7)) * 8];
            }
            #pragma unroll
            for (int j2 = 0; j2 < 4; ++j2) {
                int R = wn * 64 + j2 * 16 + fr;
                bfr[j2] = *(const bf16x8*)&Bs[R][((kk * 4 + kg) ^ (R & 7)) * 8];
            }
            #pragma unroll
            for (int i2 = 0; i2 < 4; ++i2)
                #pragma unroll
                for (int j2 = 0; j2 < 4; ++j2)
                    acc[i2][j2] = __builtin_amdgcn_mfma_f32_16x16x32_bf16(
                        af[i2], bfr[j2], acc[i2][j2], 0, 0, 0);
        }
    }

    // epilogue: C/D layout col = lane&15, row = (lane>>4)*4 + r
    const int colL = lane & 15, rgrp = (lane >> 4) * 4;
    #pragma unroll
    for (int i2 = 0; i2 < 4; ++i2) {
        #pragma unroll
        for (int r = 0; r < 4; ++r) {
            int gm = m0 + wm * 64 + i2 * 16 + rgrp + r;
            int token = gm; float sc = 1.0f;
            if (SCATTER) {
                token = tab[gm];
                if (token < 0) continue;
                sc = rs[token];
            } else if (ROWSCALE) {
                sc = rs[gm];
            }
            #pragma unroll
            for (int j2 = 0; j2 < 4; ++j2) {
                int gn = n0 + wn * 64 + j2 * 16 + colL;
                float v = acc[i2][j2][r] + bptr[gn];
                if (RELU) v = fmaxf(v, 0.0f);
                if (SCATTER) {
                    Cf[(long)token * N + gn] += v * sc;     // unique writer
                } else {
                    if (ROWSCALE) v *= sc;
                    if (OUTBF16) Cb[(long)gm * N + gn] = f2bf(v);
                    else         Cf[(long)gm * N + gn] = v;
                }
            }
        }
    }
}

// ---------------------------------------------------------------------------
// f32 -> bf16 cast (vectorized)
// ---------------------------------------------------------------------------
__global__ __launch_bounds__(256)
void cast_bf16_k(const float* __restrict__ in, unsigned short* __restrict__ out,
                 long n4)
{
    long i = (long)blockIdx.x * 256 + threadIdx.x;
    long stride = (long)gridDim.x * 256;
    for (; i < n4; i += stride) {
        float4 v = ((const float4*)in)[i];
        ushort4 o;
        o.x = f2bf(v.x); o.y = f2bf(v.y); o.z = f2bf(v.z); o.w = f2bf(v.w);
        ((ushort4*)out)[i] = o;
    }
}

// ---------------------------------------------------------------------------
// Transpose + cast: W[K][N] f32 -> Wt[N][K] bf16, 64x64 LDS tiles. z batched.
// ---------------------------------------------------------------------------
__global__ __launch_bounds__(256)
void transpose_cast_k(const float* __restrict__ W, unsigned short* __restrict__ Wt,
                      int K, int N, long wB, long wtB)
{
    const int z = blockIdx.z;
    W  += (long)z * wB;
    Wt += (long)z * wtB;
    __shared__ float tile[64][65];
    const int k0 = blockIdx.x * 64, n0 = blockIdx.y * 64;
    const int c = threadIdx.x & 63, r4 = threadIdx.x >> 6;
    #pragma unroll 4
    for (int it = 0; it < 16; ++it) {
        int row = it * 4 + r4;
        tile[row][c] = W[(long)(k0 + row) * N + n0 + c];
    }
    __syncthreads();
    #pragma unroll 4
    for (int it = 0; it < 16; ++it) {
        int nrow = it * 4 + r4;
        Wt[(long)(n0 + nrow) * K + k0 + c] = f2bf(tile[c][nrow]);
    }
}

// ---------------------------------------------------------------------------
// Wsmall: Wg'[H][8] = W_in @ W_gate, Wc'[H][2] = W_in @ W_coef  (f32)
// ---------------------------------------------------------------------------
__global__ __launch_bounds__(256)
void wsmall_k(const float* __restrict__ W_in, const float* __restrict__ W_gate,
              const float* __restrict__ W_coef,
              float* __restrict__ wgp, float* __restrict__ wcp)
{
    const int r = blockIdx.x * 4 + (threadIdx.x >> 6);
    const int lane = threadIdx.x & 63;
    float s[10] = {};
    for (int k = lane; k < HD; k += 64) {
        float a = W_in[(long)r * HD + k];
        const float4* g = (const float4*)(W_gate + (long)k * 8);
        float4 g0 = g[0], g1 = g[1];
        s[0] += a * g0.x; s[1] += a * g0.y; s[2] += a * g0.z; s[3] += a * g0.w;
        s[4] += a * g1.x; s[5] += a * g1.y; s[6] += a * g1.z; s[7] += a * g1.w;
        float2 cv = *(const float2*)(W_coef + (long)k * 2);
        s[8] += a * cv.x; s[9] += a * cv.y;
    }
    #pragma unroll
    for (int off = 32; off > 0; off >>= 1)
        #pragma unroll
        for (int e = 0; e < 10; ++e) s[e] += __shfl_xor(s[e], off);
    if (lane == 0) {
        #pragma unroll
        for (int e = 0; e < 8; ++e) wgp[(long)r * 8 + e] = s[e];
        wcp[(long)r * 2 + 0] = s[8];
        wcp[(long)r * 2 + 1] = s[9];
    }
}

// bg[8] = b_in @ W_gate ; bc[2] = b_in @ W_coef + b_coef
__global__ void gbias_k(const float* __restrict__ b_in, const float* __restrict__ W_gate,
                        const float* __restrict__ W_coef, const float* __restrict__ b_coef,
                        float* __restrict__ bg, float* __restrict__ bc)
{
    const int lane = threadIdx.x;  // 64
    float s[10] = {};
    for (int k = lane; k < HD; k += 64) {
        float a = b_in[k];
        const float4* g = (const float4*)(W_gate + (long)k * 8);
        float4 g0 = g[0], g1 = g[1];
        s[0] += a * g0.x; s[1] += a * g0.y; s[2] += a * g0.z; s[3] += a * g0.w;
        s[4] += a * g1.x; s[5] += a * g1.y; s[6] += a * g1.z; s[7] += a * g1.w;
        float2 cv = *(const float2*)(W_coef + (long)k * 2);
        s[8] += a * cv.x; s[9] += a * cv.y;
    }
    #pragma unroll
    for (int off = 32; off > 0; off >>= 1)
        #pragma unroll
        for (int e = 0; e < 10; ++e) s[e] += __shfl_xor(s[e], off);
    if (lane == 0) {
        #pragma unroll
        for (int e = 0; e < 8; ++e) bg[e] = s[e];
        bc[0] = s[8] + b_coef[0];
        bc[1] = s[9] + b_coef[1];
    }
}

// ---------------------------------------------------------------------------
// Gating from x with fused weights (one wave per token).
// ---------------------------------------------------------------------------
__global__ __launch_bounds__(256)
void gating_k(const float* __restrict__ x,
              const float* __restrict__ Wg,   // [H,8] fused
              const float* __restrict__ Wc,   // [H,2] fused
              const float* __restrict__ bg,   // [8]
              const float* __restrict__ bc,   // [2]
              int* __restrict__ eidx,
              float* __restrict__ gval,
              float* __restrict__ coef0,
              float* __restrict__ coef1)
{
    const int tok = (blockIdx.x * 256 + threadIdx.x) >> 6;
    const int lane = threadIdx.x & 63;
    const float* row = x + (long)tok * HD;

    float acc[8] = {};
    float c0 = 0.f, c1 = 0.f;
    for (int i = 0; i < HD / 64; ++i) {
        int k = i * 64 + lane;
        float tv = row[k];
        const float4* wg = (const float4*)(Wg + (long)k * 8);
        float4 w0 = wg[0], w1 = wg[1];
        acc[0] = fmaf(tv, w0.x, acc[0]); acc[1] = fmaf(tv, w0.y, acc[1]);
        acc[2] = fmaf(tv, w0.z, acc[2]); acc[3] = fmaf(tv, w0.w, acc[3]);
        acc[4] = fmaf(tv, w1.x, acc[4]); acc[5] = fmaf(tv, w1.y, acc[5]);
        acc[6] = fmaf(tv, w1.z, acc[6]); acc[7] = fmaf(tv, w1.w, acc[7]);
        float2 wcv = *(const float2*)(Wc + (long)k * 2);
        c0 = fmaf(tv, wcv.x, c0);
        c1 = fmaf(tv, wcv.y, c1);
    }
    #pragma unroll
    for (int off = 32; off > 0; off >>= 1) {
        #pragma unroll
        for (int e = 0; e < 8; ++e) acc[e] += __shfl_xor(acc[e], off);
        c0 += __shfl_xor(c0, off);
        c1 += __shfl_xor(c1, off);
    }
    if (lane == 0) {
        #pragma unroll
        for (int e = 0; e < 8; ++e) acc[e] += bg[e];
        float m = acc[0]; int best = 0;
        #pragma unroll
        for (int e = 1; e < 8; ++e) if (acc[e] > m) { m = acc[e]; best = e; }
        float s = 0.f;
        #pragma unroll
        for (int e = 0; e < 8; ++e) s += expf(acc[e] - m);
        eidx[tok] = best;
        gval[tok] = 1.0f / s;
        float l0 = c0 + bc[0], l1 = c1 + bc[1];
        float mm = fmaxf(l0, l1);
        float e0 = expf(l0 - mm), e1 = expf(l1 - mm);
        float inv = 1.0f / (e0 + e1);
        coef0[tok] = e0 * inv;
        coef1[tok] = e1 * inv;
    }
}

// ---------------------------------------------------------------------------
// Parallel capacity scan, 3 phases (integer-exact, verified round 5).
// ---------------------------------------------------------------------------
__global__ void scan_hist_k(const int* __restrict__ eidx,
                            int* __restrict__ counts,
                            int* __restrict__ idxTab)
{
    const int b = blockIdx.x;          // chunk id, 0..255
    const int lane = threadIdx.x;      // 64
    for (int j = b * 64 + lane; j < NE * CAP; j += NCHUNK * 64)
        idxTab[j] = -1;
    int e = eidx[b * 64 + lane];
    #pragma unroll
    for (int ex = 0; ex < NE; ++ex) {
        unsigned long long msk = __ballot(e == ex);
        if (lane == ex) counts[b * NE + ex] = (int)__popcll(msk);
    }
}

__global__ void scan_offsets_k(const int* __restrict__ counts,
                               int* __restrict__ offsets)
{
    const int e = threadIdx.x;         // 64 threads, 8 active
    if (e < NE) {
        int run = 0;
        for (int b = 0; b < NCHUNK; ++b) {
            offsets[b * NE + e] = run;
            run += counts[b * NE + e];
        }
    }
}

__global__ void scan_fill_k(const int* __restrict__ eidx,
                            const float* __restrict__ gval,
                            const float* __restrict__ coef0,
                            const int* __restrict__ offsets,
                            int* __restrict__ idxTab,
                            float* __restrict__ smoe)
{
    const int b = blockIdx.x;
    const int lane = threadIdx.x;
    const int tok = b * 64 + lane;
    int e = eidx[tok];
    unsigned long long below = (lane == 0) ? 0ull : ((~0ull) >> (64 - lane));
    int myrank = 0;
    #pragma unroll
    for (int ex = 0; ex < NE; ++ex) {
        unsigned long long msk = __ballot(e == ex);
        if (e == ex) myrank = (int)__popcll(msk & below) + offsets[b * NE + ex];
    }
    if (myrank < CAP) {
        idxTab[e * CAP + myrank] = tok;
        smoe[tok] = gval[tok] * coef0[tok];
    } else {
        smoe[tok] = 0.0f;
    }
}

// ---------------------------------------------------------------------------
// Workspace plan (lifetime-aliased; ~134.8 MB):
//   slotA [0,32Mi):   W1T then res1 then mixb
//   h     [32,72Mi);  t_b [72,104Mi); W2T [104,120Mi);
//   WinT/Wr1T/Wr2T/WoutT [120..128Mi); small [128Mi..)
//   xb: d_out[0,32Mi);  mix: d_out f32;  out: d_out
// ---------------------------------------------------------------------------
extern "C" void kernel_launch(void* const* d_in, const int* in_sizes, int n_in,
                              void* d_out, int out_size, void* d_ws, size_t ws_size,
                              hipStream_t stream)
{
    const float* x      = (const float*)d_in[0];
    const float* W_in   = (const float*)d_in[1];
    const float* b_in   = (const float*)d_in[2];
    const float* W_gate = (const float*)d_in[3];
    const float* W1     = (const float*)d_in[4];
    const float* b1     = (const float*)d_in[5];
    const float* W2     = (const float*)d_in[6];
    const float* b2     = (const float*)d_in[7];
    const float* Wr1    = (const float*)d_in[8];
    const float* br1    = (const float*)d_in[9];
    const float* Wr2    = (const float*)d_in[10];
    const float* br2    = (const float*)d_in[11];
    const float* W_coef = (const float*)d_in[12];
    const float* b_coef = (const float*)d_in[13];
    const float* W_out  = (const float*)d_in[14];
    const float* b_out  = (const float*)d_in[15];
    float* out = (float*)d_out;

    const size_t MiB = 1024 * 1024;
    char* ws = (char*)d_ws;
    unsigned short* W1T  = (unsigned short*)(ws + 0);          // 16 MiB
    unsigned short* res1 = (unsigned short*)(ws + 0);          // 32 MiB (after FC1)
    unsigned short* mixb = (unsigned short*)(ws + 0);          // 32 MiB (after res-mix)
    unsigned short* h    = (unsigned short*)(ws + 32 * MiB);   // 40 MiB
    unsigned short* t_b  = (unsigned short*)(ws + 72 * MiB);   // 32 MiB
    unsigned short* W2T  = (unsigned short*)(ws + 104 * MiB);  // 16 MiB
    unsigned short* WinT = (unsigned short*)(ws + 120 * MiB);  // 2 MiB
    unsigned short* Wr1T = (unsigned short*)(ws + 122 * MiB);  // 2 MiB
    unsigned short* Wr2T = (unsigned short*)(ws + 124 * MiB);  // 2 MiB
    unsigned short* WoutT= (unsigned short*)(ws + 126 * MiB);  // 2 MiB
    char* sm = ws + 128 * MiB;
    float* wgp  = (float*)(sm);            sm += HD * 8 * 4;
    float* wcp  = (float*)(sm);            sm += HD * 2 * 4;
    float* bg   = (float*)(sm);            sm += 64;
    float* bc   = (float*)(sm);            sm += 64;
    int*   eidx = (int*)(sm);              sm += T_TOK * 4;
    float* gval = (float*)(sm);            sm += T_TOK * 4;
    float* cf0  = (float*)(sm);            sm += T_TOK * 4;
    float* cf1  = (float*)(sm);            sm += T_TOK * 4;
    float* smoe = (float*)(sm);            sm += T_TOK * 4;
    int* idxTab = (int*)(sm);              sm += NE * CAP * 4;
    int* counts = (int*)(sm);              sm += NCHUNK * NE * 4;
    int* offs   = (int*)(sm);              sm += NCHUNK * NE * 4;
    unsigned short* xb = (unsigned short*)d_out;   // 32 MiB, dies before mix
    float* mix = out;                               // f32
    (void)ws_size; (void)in_sizes; (void)n_in; (void)out_size;

    dim3 blk(256);
    dim3 blkG(512);
    dim3 gT(16, 16, 1);
    dim3 gT8(16, 16, 8);
    dim3 gBig(HD / 128, T_TOK / 256, 1);   // 8 x 64 = 512 blocks (%8==0)
    dim3 gExp(HD / 128, CAP / 256, NE);    // 8 x 10 x 8 = 640 blocks (%8==0)

    // a. xb = bf16(x)
    cast_bf16_k<<<2048, blk, 0, stream>>>(x, xb, (long)T_TOK * HD / 4);
    // b. weight transposes (bf16 [N][K])
    transpose_cast_k<<<gT,  blk, 0, stream>>>(W_in,  WinT,  HD, HD, 0, 0);
    transpose_cast_k<<<gT,  blk, 0, stream>>>(Wr1,   Wr1T,  HD, HD, 0, 0);
    transpose_cast_k<<<gT,  blk, 0, stream>>>(Wr2,   Wr2T,  HD, HD, 0, 0);
    transpose_cast_k<<<gT,  blk, 0, stream>>>(W_out, WoutT, HD, HD, 0, 0);
    transpose_cast_k<<<gT8, blk, 0, stream>>>(W1, W1T, HD, HD, (long)HD * HD, (long)HD * HD);
    transpose_cast_k<<<gT8, blk, 0, stream>>>(W2, W2T, HD, HD, (long)HD * HD, (long)HD * HD);
    // c. fused gating weights (f32)
    wsmall_k<<<HD / 4, blk, 0, stream>>>(W_in, W_gate, W_coef, wgp, wcp);
    gbias_k<<<1, 64, 0, stream>>>(b_in, W_gate, W_coef, b_coef, bg, bc);
    // d. gating from x (f32 path for discrete routing)
    gating_k<<<T_TOK / 4, blk, 0, stream>>>(x, wgp, wcp, bg, bc, eidx, gval, cf0, cf1);
    // e. parallel capacity scan
    scan_hist_k<<<NCHUNK, 64, 0, stream>>>(eidx, counts, idxTab);
    scan_offsets_k<<<1, 64, 0, stream>>>(counts, offs);
    scan_fill_k<<<NCHUNK, 64, 0, stream>>>(eidx, gval, cf0, offs, idxTab, smoe);
    // f. t_b = bf16(xb @ W_in + b_in)
    gemm_bf16_k<false, false, false, false, true><<<gBig, blkG, 0, stream>>>(
        xb, WinT, b_in, t_b, T_TOK, HD, HD, nullptr, nullptr, 0, 0, 0, 0, 0);
    // h. h[e] = relu(gather(t_b) @ W1[e] + b1[e])   bf16 out
    gemm_bf16_k<true, true, false, false, true><<<gExp, blkG, 0, stream>>>(
        t_b, W1T, b1, h, CAP, HD, HD, idxTab, nullptr,
        0, (long)HD * HD, HD, CAP, (long)CAP * HD);
    // i. res1 = relu(t_b @ Wr1 + br1)   bf16 out (overlays W1T slot)
    gemm_bf16_k<false, true, false, false, true><<<gBig, blkG, 0, stream>>>(
        t_b, Wr1T, br1, res1, T_TOK, HD, HD, nullptr, nullptr, 0, 0, 0, 0, 0);
    // j. mix = (res1 @ Wr2 + br2) * cf1[row]   f32 -> d_out
    gemm_bf16_k<false, false, true, false, false><<<gBig, blkG, 0, stream>>>(
        res1, Wr2T, br2, mix, T_TOK, HD, HD, nullptr, cf1, 0, 0, 0, 0, 0);
    // k. mix[tok] += (h[e] @ W2[e] + b2[e]) * smoe[tok]   f32 RMW
    gemm_bf16_k<false, false, false, true, false><<<gExp, blkG, 0, stream>>>(
        h, W2T, b2, mix, CAP, HD, HD, idxTab, smoe,
        (long)CAP * HD, (long)HD * HD, HD, CAP, 0);
    // l. mixb = bf16(mix)
    cast_bf16_k<<<2048, blk, 0, stream>>>(mix, mixb, (long)T_TOK * HD / 4);
    // m. out = mixb @ W_out + b_out   f32 -> d_out
    gemm_bf16_k<false, false, false, false, false><<<gBig, blkG, 0, stream>>>(
        mixb, WoutT, b_out, out, T_TOK, HD, HD, nullptr, nullptr, 0, 0, 0, 0, 0);
}

// Round 10
// 405.282 us; speedup vs baseline: 1.1313x; 1.0333x over previous
//
#include <hip/hip_runtime.h>
#include <cstdint>

// Problem constants (static per reference)
#define T_TOK 16384     // B*S
#define HD    1024      // H
#define NE    8         // experts
#define CAP   2560      // ceil(1.25*T/E)
#define NCHUNK (T_TOK / 64)   // 256

typedef __attribute__((ext_vector_type(4))) float f32x4;
typedef __attribute__((ext_vector_type(8))) short bf16x8;   // 8 bf16 = 4 VGPRs

__device__ __forceinline__ unsigned short f2bf(float f) {
    union { float f; unsigned u; } x{f};
    unsigned r = x.u + 0x7FFF + ((x.u >> 16) & 1);   // RNE
    return (unsigned short)(r >> 16);
}

__device__ __forceinline__ void gload_lds16(const unsigned short* g, unsigned short* l) {
    __builtin_amdgcn_global_load_lds(
        (const __attribute__((address_space(1))) void*)g,
        (__attribute__((address_space(3))) void*)l, 16, 0, 0);
}

// ---------------------------------------------------------------------------
// bf16 MFMA GEMM: C[M,N] = op(A[M,K] @ Bt[N,K]^T + bias[N])
// R9 structure (best measured): 256x128 tile, BK=64, 8 waves (4m x 2n),
// single-buffer 2-barrier loop, XCD bijective swizzle, XOR chunk-swizzle.
// R10: SCATTER+OUTBF16 epilogue variant — writes bf16 C = f2bf(addsrc + v*sc)
// (fuses the former mix->mixb cast into the scatter GEMM; unique writer per
// element, dropped-token rows handled by drop_cast_k).
// ---------------------------------------------------------------------------
template<bool GATHER, bool RELU, bool ROWSCALE, bool SCATTER, bool OUTBF16>
__global__ __launch_bounds__(512)
void gemm_bf16_k(const unsigned short* __restrict__ A,
                 const unsigned short* __restrict__ Bt,
                 const float* __restrict__ bias,
                 void* __restrict__ Cv,
                 int M, int N, int K,
                 const int* __restrict__ idxTab,
                 const float* __restrict__ rs,
                 const float* __restrict__ addsrc,
                 long aB, long bB, long biasB, long tabB, long cB)
{
    // ---- XCD-aware remap: XCD c gets contiguous logical chunk ----
    const int nx = gridDim.x, ny = gridDim.y;
    long nwg = (long)nx * ny * gridDim.z;
    long flat = blockIdx.x + (long)nx * (blockIdx.y + (long)ny * blockIdx.z);
    long cpx = nwg >> 3;                       // nwg % 8 == 0 by construction
    long swz = (flat & 7) * cpx + (flat >> 3);
    const int bx = (int)(swz % nx);
    const int by = (int)((swz / nx) % ny);
    const int bz = (int)(swz / ((long)nx * ny));

    A  += (long)bz * aB;
    Bt += (long)bz * bB;
    const float* bptr = bias + (long)bz * biasB;
    const int* tab = idxTab ? idxTab + (long)bz * tabB : nullptr;
    float*          Cf = (float*)Cv + (long)bz * cB;
    unsigned short* Cb = (unsigned short*)Cv + (long)bz * cB;

    __shared__ unsigned short As[256][64];   // 32 KB, row = m
    __shared__ unsigned short Bs[128][64];   // 16 KB, row = n  (48 KB total)

    const int tid  = threadIdx.x;
    const int wv   = tid >> 6;               // 0..7
    const int lane = tid & 63;
    const int m0 = by * 256, n0 = bx * 128;

    // staging: issue = 8 rows x 128 B = 1024 B = 64 lanes x 16 B.
    const int srow = lane >> 3;
    const int schk = lane & 7;

    const unsigned short* aSrc[4];           // wave stages A rows wv*32..+31
    const unsigned short* bSrc[2];           // wave stages B rows wv*16..+15
    #pragma unroll
    for (int i = 0; i < 4; ++i) {
        int lrow = wv * 32 + i * 8 + srow;          // 0..255
        int scol = ((schk ^ (lrow & 7)) * 8);       // swizzled col (elems)
        long sr;
        if (GATHER) { int tr = tab[m0 + lrow]; sr = tr < 0 ? 0 : tr; }
        else        sr = m0 + lrow;
        aSrc[i] = A + sr * (long)K + scol;
    }
    #pragma unroll
    for (int i = 0; i < 2; ++i) {
        int lrow = wv * 16 + i * 8 + srow;          // 0..127
        int scol = ((schk ^ (lrow & 7)) * 8);
        bSrc[i] = Bt + (long)(n0 + lrow) * K + scol;
    }

    f32x4 acc[4][4] = {};
    const int wm = wv >> 1, wn = wv & 1;     // 4 x 2 wave grid
    const int fr = lane & 15, kg = lane >> 4;

    for (int k0 = 0; k0 < K; k0 += 64) {
        __syncthreads();                     // prev tile fully consumed
        #pragma unroll
        for (int i = 0; i < 4; ++i)
            gload_lds16(aSrc[i] + k0, &As[wv * 32 + i * 8][0]);
        #pragma unroll
        for (int i = 0; i < 2; ++i)
            gload_lds16(bSrc[i] + k0, &Bs[wv * 16 + i * 8][0]);
        __syncthreads();                     // vmcnt(0) drained here

        #pragma unroll
        for (int kk = 0; kk < 2; ++kk) {     // two K=32 halves of BK=64
            bf16x8 af[4], bfr[4];
            #pragma unroll
            for (int i2 = 0; i2 < 4; ++i2) {
                int R = wm * 64 + i2 * 16 + fr;
                af[i2] = *(const bf16x8*)&As[R][((kk * 4 + kg) ^ (R & 7)) * 8];
            }
            #pragma unroll
            for (int j2 = 0; j2 < 4; ++j2) {
                int R = wn * 64 + j2 * 16 + fr;
                bfr[j2] = *(const bf16x8*)&Bs[R][((kk * 4 + kg) ^ (R & 7)) * 8];
            }
            #pragma unroll
            for (int i2 = 0; i2 < 4; ++i2)
                #pragma unroll
                for (int j2 = 0; j2 < 4; ++j2)
                    acc[i2][j2] = __builtin_amdgcn_mfma_f32_16x16x32_bf16(
                        af[i2], bfr[j2], acc[i2][j2], 0, 0, 0);
        }
    }

    // epilogue: C/D layout col = lane&15, row = (lane>>4)*4 + r
    const int colL = lane & 15, rgrp = (lane >> 4) * 4;
    #pragma unroll
    for (int i2 = 0; i2 < 4; ++i2) {
        #pragma unroll
        for (int r = 0; r < 4; ++r) {
            int gm = m0 + wm * 64 + i2 * 16 + rgrp + r;
            int token = gm; float sc = 1.0f;
            if (SCATTER) {
                token = tab[gm];
                if (token < 0) continue;
                sc = rs[token];
            } else if (ROWSCALE) {
                sc = rs[gm];
            }
            #pragma unroll
            for (int j2 = 0; j2 < 4; ++j2) {
                int gn = n0 + wn * 64 + j2 * 16 + colL;
                float v = acc[i2][j2][r] + bptr[gn];
                if (RELU) v = fmaxf(v, 0.0f);
                if (SCATTER) {
                    long idx = (long)token * N + gn;
                    if (OUTBF16) Cb[idx] = f2bf(addsrc[idx] + v * sc);  // fused cast
                    else         Cf[idx] += v * sc;                     // f32 RMW
                } else {
                    if (ROWSCALE) v *= sc;
                    if (OUTBF16) Cb[(long)gm * N + gn] = f2bf(v);
                    else         Cf[(long)gm * N + gn] = v;
                }
            }
        }
    }
}

// ---------------------------------------------------------------------------
// Dropped-token rows: mixb[row] = bf16(mix[row]) for rows never touched by
// the scatter GEMM. One row per block-iteration; count is device-side.
// ---------------------------------------------------------------------------
__global__ __launch_bounds__(256)
void drop_cast_k(const float* __restrict__ mix, unsigned short* __restrict__ mixb,
                 const int* __restrict__ droplist, const int* __restrict__ dropcnt)
{
    const int cnt = *dropcnt;
    for (int i = blockIdx.x; i < cnt; i += gridDim.x) {
        const int tok = droplist[i];
        const float4* src = (const float4*)(mix + (long)tok * HD);
        ushort4* dst = (ushort4*)(mixb + (long)tok * HD);
        const int j = threadIdx.x;          // 256 threads x 4 elems = 1024
        float4 v = src[j];
        ushort4 o;
        o.x = f2bf(v.x); o.y = f2bf(v.y); o.z = f2bf(v.z); o.w = f2bf(v.w);
        dst[j] = o;
    }
}

// ---------------------------------------------------------------------------
// Transpose + cast: W[K][N] f32 -> Wt[N][K] bf16, 64x64 LDS tiles. z batched.
// ---------------------------------------------------------------------------
__global__ __launch_bounds__(256)
void transpose_cast_k(const float* __restrict__ W, unsigned short* __restrict__ Wt,
                      int K, int N, long wB, long wtB)
{
    const int z = blockIdx.z;
    W  += (long)z * wB;
    Wt += (long)z * wtB;
    __shared__ float tile[64][65];
    const int k0 = blockIdx.x * 64, n0 = blockIdx.y * 64;
    const int c = threadIdx.x & 63, r4 = threadIdx.x >> 6;
    #pragma unroll 4
    for (int it = 0; it < 16; ++it) {
        int row = it * 4 + r4;
        tile[row][c] = W[(long)(k0 + row) * N + n0 + c];
    }
    __syncthreads();
    #pragma unroll 4
    for (int it = 0; it < 16; ++it) {
        int nrow = it * 4 + r4;
        Wt[(long)(n0 + nrow) * K + k0 + c] = f2bf(tile[c][nrow]);
    }
}

// ---------------------------------------------------------------------------
// Wsmall: Wg'[H][8] = W_in @ W_gate, Wc'[H][2] = W_in @ W_coef  (f32)
// ---------------------------------------------------------------------------
__global__ __launch_bounds__(256)
void wsmall_k(const float* __restrict__ W_in, const float* __restrict__ W_gate,
              const float* __restrict__ W_coef,
              float* __restrict__ wgp, float* __restrict__ wcp)
{
    const int r = blockIdx.x * 4 + (threadIdx.x >> 6);
    const int lane = threadIdx.x & 63;
    float s[10] = {};
    for (int k = lane; k < HD; k += 64) {
        float a = W_in[(long)r * HD + k];
        const float4* g = (const float4*)(W_gate + (long)k * 8);
        float4 g0 = g[0], g1 = g[1];
        s[0] += a * g0.x; s[1] += a * g0.y; s[2] += a * g0.z; s[3] += a * g0.w;
        s[4] += a * g1.x; s[5] += a * g1.y; s[6] += a * g1.z; s[7] += a * g1.w;
        float2 cv = *(const float2*)(W_coef + (long)k * 2);
        s[8] += a * cv.x; s[9] += a * cv.y;
    }
    #pragma unroll
    for (int off = 32; off > 0; off >>= 1)
        #pragma unroll
        for (int e = 0; e < 10; ++e) s[e] += __shfl_xor(s[e], off);
    if (lane == 0) {
        #pragma unroll
        for (int e = 0; e < 8; ++e) wgp[(long)r * 8 + e] = s[e];
        wcp[(long)r * 2 + 0] = s[8];
        wcp[(long)r * 2 + 1] = s[9];
    }
}

// bg[8] = b_in @ W_gate ; bc[2] = b_in @ W_coef + b_coef
__global__ void gbias_k(const float* __restrict__ b_in, const float* __restrict__ W_gate,
                        const float* __restrict__ W_coef, const float* __restrict__ b_coef,
                        float* __restrict__ bg, float* __restrict__ bc)
{
    const int lane = threadIdx.x;  // 64
    float s[10] = {};
    for (int k = lane; k < HD; k += 64) {
        float a = b_in[k];
        const float4* g = (const float4*)(W_gate + (long)k * 8);
        float4 g0 = g[0], g1 = g[1];
        s[0] += a * g0.x; s[1] += a * g0.y; s[2] += a * g0.z; s[3] += a * g0.w;
        s[4] += a * g1.x; s[5] += a * g1.y; s[6] += a * g1.z; s[7] += a * g1.w;
        float2 cv = *(const float2*)(W_coef + (long)k * 2);
        s[8] += a * cv.x; s[9] += a * cv.y;
    }
    #pragma unroll
    for (int off = 32; off > 0; off >>= 1)
        #pragma unroll
        for (int e = 0; e < 10; ++e) s[e] += __shfl_xor(s[e], off);
    if (lane == 0) {
        #pragma unroll
        for (int e = 0; e < 8; ++e) bg[e] = s[e];
        bc[0] = s[8] + b_coef[0];
        bc[1] = s[9] + b_coef[1];
    }
}

// ---------------------------------------------------------------------------
// Gating from x with fused weights (one wave per token).
// R10: also emits xb = bf16(x) while the row streams through registers
// (eliminates the separate 96 MB cast pass).
// ---------------------------------------------------------------------------
__global__ __launch_bounds__(256)
void gating_k(const float* __restrict__ x,
              const float* __restrict__ Wg,   // [H,8] fused
              const float* __restrict__ Wc,   // [H,2] fused
              const float* __restrict__ bg,   // [8]
              const float* __restrict__ bc,   // [2]
              unsigned short* __restrict__ xb,
              int* __restrict__ eidx,
              float* __restrict__ gval,
              float* __restrict__ coef0,
              float* __restrict__ coef1)
{
    const int tok = (blockIdx.x * 256 + threadIdx.x) >> 6;
    const int lane = threadIdx.x & 63;
    const float* row = x + (long)tok * HD;
    unsigned short* orow = xb + (long)tok * HD;

    float acc[8] = {};
    float c0 = 0.f, c1 = 0.f;
    for (int i = 0; i < HD / 64; ++i) {
        int k = i * 64 + lane;
        float tv = row[k];
        orow[k] = f2bf(tv);                      // fused x -> bf16 (coalesced)
        const float4* wg = (const float4*)(Wg + (long)k * 8);
        float4 w0 = wg[0], w1 = wg[1];
        acc[0] = fmaf(tv, w0.x, acc[0]); acc[1] = fmaf(tv, w0.y, acc[1]);
        acc[2] = fmaf(tv, w0.z, acc[2]); acc[3] = fmaf(tv, w0.w, acc[3]);
        acc[4] = fmaf(tv, w1.x, acc[4]); acc[5] = fmaf(tv, w1.y, acc[5]);
        acc[6] = fmaf(tv, w1.z, acc[6]); acc[7] = fmaf(tv, w1.w, acc[7]);
        float2 wcv = *(const float2*)(Wc + (long)k * 2);
        c0 = fmaf(tv, wcv.x, c0);
        c1 = fmaf(tv, wcv.y, c1);
    }
    #pragma unroll
    for (int off = 32; off > 0; off >>= 1) {
        #pragma unroll
        for (int e = 0; e < 8; ++e) acc[e] += __shfl_xor(acc[e], off);
        c0 += __shfl_xor(c0, off);
        c1 += __shfl_xor(c1, off);
    }
    if (lane == 0) {
        #pragma unroll
        for (int e = 0; e < 8; ++e) acc[e] += bg[e];
        float m = acc[0]; int best = 0;
        #pragma unroll
        for (int e = 1; e < 8; ++e) if (acc[e] > m) { m = acc[e]; best = e; }
        float s = 0.f;
        #pragma unroll
        for (int e = 0; e < 8; ++e) s += expf(acc[e] - m);
        eidx[tok] = best;
        gval[tok] = 1.0f / s;
        float l0 = c0 + bc[0], l1 = c1 + bc[1];
        float mm = fmaxf(l0, l1);
        float e0 = expf(l0 - mm), e1 = expf(l1 - mm);
        float inv = 1.0f / (e0 + e1);
        coef0[tok] = e0 * inv;
        coef1[tok] = e1 * inv;
    }
}

// ---------------------------------------------------------------------------
// Parallel capacity scan, 3 phases (integer-exact, verified round 5).
// R10: scan_fill also appends dropped tokens to droplist (set-deterministic).
// ---------------------------------------------------------------------------
__global__ void scan_hist_k(const int* __restrict__ eidx,
                            int* __restrict__ counts,
                            int* __restrict__ idxTab)
{
    const int b = blockIdx.x;          // chunk id, 0..255
    const int lane = threadIdx.x;      // 64
    for (int j = b * 64 + lane; j < NE * CAP; j += NCHUNK * 64)
        idxTab[j] = -1;
    int e = eidx[b * 64 + lane];
    #pragma unroll
    for (int ex = 0; ex < NE; ++ex) {
        unsigned long long msk = __ballot(e == ex);
        if (lane == ex) counts[b * NE + ex] = (int)__popcll(msk);
    }
}

__global__ void scan_offsets_k(const int* __restrict__ counts,
                               int* __restrict__ offsets,
                               int* __restrict__ dropcnt)
{
    const int e = threadIdx.x;         // 64 threads, 8 active
    if (e == 63) *dropcnt = 0;         // runs before scan_fill_k
    if (e < NE) {
        int run = 0;
        for (int b = 0; b < NCHUNK; ++b) {
            offsets[b * NE + e] = run;
            run += counts[b * NE + e];
        }
    }
}

__global__ void scan_fill_k(const int* __restrict__ eidx,
                            const float* __restrict__ gval,
                            const float* __restrict__ coef0,
                            const int* __restrict__ offsets,
                            int* __restrict__ idxTab,
                            float* __restrict__ smoe,
                            int* __restrict__ droplist,
                            int* __restrict__ dropcnt)
{
    const int b = blockIdx.x;
    const int lane = threadIdx.x;
    const int tok = b * 64 + lane;
    int e = eidx[tok];
    unsigned long long below = (lane == 0) ? 0ull : ((~0ull) >> (64 - lane));
    int myrank = 0;
    #pragma unroll
    for (int ex = 0; ex < NE; ++ex) {
        unsigned long long msk = __ballot(e == ex);
        if (e == ex) myrank = (int)__popcll(msk & below) + offsets[b * NE + ex];
    }
    if (myrank < CAP) {
        idxTab[e * CAP + myrank] = tok;
        smoe[tok] = gval[tok] * coef0[tok];
    } else {
        smoe[tok] = 0.0f;
        int di = atomicAdd(dropcnt, 1);    // order varies; content is a set
        droplist[di] = tok;
    }
}

// ---------------------------------------------------------------------------
// Workspace plan (lifetime-aliased; ~135 MB):
//   slotA [0,32Mi):   W1T (b..h) then res1 (i..j) then mixb (k..m)
//   h     [32,72Mi);  t_b [72,104Mi); W2T [104,120Mi);
//   WinT/Wr1T/Wr2T/WoutT [120..128Mi); small [128Mi..)
//   xb: d_out[0,32Mi) (d..f);  mix: d_out f32 (j..m, read-only after j);
//   out: d_out (m)
// ---------------------------------------------------------------------------
extern "C" void kernel_launch(void* const* d_in, const int* in_sizes, int n_in,
                              void* d_out, int out_size, void* d_ws, size_t ws_size,
                              hipStream_t stream)
{
    const float* x      = (const float*)d_in[0];
    const float* W_in   = (const float*)d_in[1];
    const float* b_in   = (const float*)d_in[2];
    const float* W_gate = (const float*)d_in[3];
    const float* W1     = (const float*)d_in[4];
    const float* b1     = (const float*)d_in[5];
    const float* W2     = (const float*)d_in[6];
    const float* b2     = (const float*)d_in[7];
    const float* Wr1    = (const float*)d_in[8];
    const float* br1    = (const float*)d_in[9];
    const float* Wr2    = (const float*)d_in[10];
    const float* br2    = (const float*)d_in[11];
    const float* W_coef = (const float*)d_in[12];
    const float* b_coef = (const float*)d_in[13];
    const float* W_out  = (const float*)d_in[14];
    const float* b_out  = (const float*)d_in[15];
    float* out = (float*)d_out;

    const size_t MiB = 1024 * 1024;
    char* ws = (char*)d_ws;
    unsigned short* W1T  = (unsigned short*)(ws + 0);          // 16 MiB
    unsigned short* res1 = (unsigned short*)(ws + 0);          // 32 MiB (after FC1)
    unsigned short* mixb = (unsigned short*)(ws + 0);          // 32 MiB (after res-mix)
    unsigned short* h    = (unsigned short*)(ws + 32 * MiB);   // 40 MiB
    unsigned short* t_b  = (unsigned short*)(ws + 72 * MiB);   // 32 MiB
    unsigned short* W2T  = (unsigned short*)(ws + 104 * MiB);  // 16 MiB
    unsigned short* WinT = (unsigned short*)(ws + 120 * MiB);  // 2 MiB
    unsigned short* Wr1T = (unsigned short*)(ws + 122 * MiB);  // 2 MiB
    unsigned short* Wr2T = (unsigned short*)(ws + 124 * MiB);  // 2 MiB
    unsigned short* WoutT= (unsigned short*)(ws + 126 * MiB);  // 2 MiB
    char* sm = ws + 128 * MiB;
    float* wgp  = (float*)(sm);            sm += HD * 8 * 4;
    float* wcp  = (float*)(sm);            sm += HD * 2 * 4;
    float* bg   = (float*)(sm);            sm += 64;
    float* bc   = (float*)(sm);            sm += 64;
    int*   eidx = (int*)(sm);              sm += T_TOK * 4;
    float* gval = (float*)(sm);            sm += T_TOK * 4;
    float* cf0  = (float*)(sm);            sm += T_TOK * 4;
    float* cf1  = (float*)(sm);            sm += T_TOK * 4;
    float* smoe = (float*)(sm);            sm += T_TOK * 4;
    int* idxTab = (int*)(sm);              sm += NE * CAP * 4;
    int* counts = (int*)(sm);              sm += NCHUNK * NE * 4;
    int* offs   = (int*)(sm);              sm += NCHUNK * NE * 4;
    int* droplist = (int*)(sm);            sm += T_TOK * 4;
    int* dropcnt  = (int*)(sm);            sm += 64;
    unsigned short* xb = (unsigned short*)d_out;   // 32 MiB, dies after f
    float* mix = out;                               // f32, written j, read k/m
    (void)ws_size; (void)in_sizes; (void)n_in; (void)out_size;

    dim3 blk(256);
    dim3 blkG(512);
    dim3 gT(16, 16, 1);
    dim3 gT8(16, 16, 8);
    dim3 gBig(HD / 128, T_TOK / 256, 1);   // 8 x 64 = 512 blocks (%8==0)
    dim3 gExp(HD / 128, CAP / 256, NE);    // 8 x 10 x 8 = 640 blocks (%8==0)

    // b. weight transposes (bf16 [N][K])
    transpose_cast_k<<<gT,  blk, 0, stream>>>(W_in,  WinT,  HD, HD, 0, 0);
    transpose_cast_k<<<gT,  blk, 0, stream>>>(Wr1,   Wr1T,  HD, HD, 0, 0);
    transpose_cast_k<<<gT,  blk, 0, stream>>>(Wr2,   Wr2T,  HD, HD, 0, 0);
    transpose_cast_k<<<gT,  blk, 0, stream>>>(W_out, WoutT, HD, HD, 0, 0);
    transpose_cast_k<<<gT8, blk, 0, stream>>>(W1, W1T, HD, HD, (long)HD * HD, (long)HD * HD);
    transpose_cast_k<<<gT8, blk, 0, stream>>>(W2, W2T, HD, HD, (long)HD * HD, (long)HD * HD);
    // c. fused gating weights (f32)
    wsmall_k<<<HD / 4, blk, 0, stream>>>(W_in, W_gate, W_coef, wgp, wcp);
    gbias_k<<<1, 64, 0, stream>>>(b_in, W_gate, W_coef, b_coef, bg, bc);
    // d. gating from x (f32 routing path) + fused x->bf16 cast
    gating_k<<<T_TOK / 4, blk, 0, stream>>>(x, wgp, wcp, bg, bc, xb,
                                            eidx, gval, cf0, cf1);
    // e. parallel capacity scan (+ dropped-token list)
    scan_hist_k<<<NCHUNK, 64, 0, stream>>>(eidx, counts, idxTab);
    scan_offsets_k<<<1, 64, 0, stream>>>(counts, offs, dropcnt);
    scan_fill_k<<<NCHUNK, 64, 0, stream>>>(eidx, gval, cf0, offs, idxTab, smoe,
                                           droplist, dropcnt);
    // f. t_b = bf16(xb @ W_in + b_in)
    gemm_bf16_k<false, false, false, false, true><<<gBig, blkG, 0, stream>>>(
        xb, WinT, b_in, t_b, T_TOK, HD, HD, nullptr, nullptr, nullptr,
        0, 0, 0, 0, 0);
    // h. h[e] = relu(gather(t_b) @ W1[e] + b1[e])   bf16 out
    gemm_bf16_k<true, true, false, false, true><<<gExp, blkG, 0, stream>>>(
        t_b, W1T, b1, h, CAP, HD, HD, idxTab, nullptr, nullptr,
        0, (long)HD * HD, HD, CAP, (long)CAP * HD);
    // i. res1 = relu(t_b @ Wr1 + br1)   bf16 out (overlays W1T slot)
    gemm_bf16_k<false, true, false, false, true><<<gBig, blkG, 0, stream>>>(
        t_b, Wr1T, br1, res1, T_TOK, HD, HD, nullptr, nullptr, nullptr,
        0, 0, 0, 0, 0);
    // j. mix = (res1 @ Wr2 + br2) * cf1[row]   f32 -> d_out
    gemm_bf16_k<false, false, true, false, false><<<gBig, blkG, 0, stream>>>(
        res1, Wr2T, br2, mix, T_TOK, HD, HD, nullptr, cf1, nullptr,
        0, 0, 0, 0, 0);
    // k. mixb[tok] = bf16(mix[tok] + (h[e]@W2[e]+b2[e])*smoe[tok])  fused cast
    gemm_bf16_k<false, false, false, true, true><<<gExp, blkG, 0, stream>>>(
        h, W2T, b2, mixb, CAP, HD, HD, idxTab, smoe, mix,
        (long)CAP * HD, (long)HD * HD, HD, CAP, 0);
    // k2. dropped-token rows: mixb = bf16(mix)
    drop_cast_k<<<256, blk, 0, stream>>>(mix, mixb, droplist, dropcnt);
    // m. out = mixb @ W_out + b_out   f32 -> d_out
    gemm_bf16_k<false, false, false, false, false><<<gBig, blkG, 0, stream>>>(
        mixb, WoutT, b_out, out, T_TOK, HD, HD, nullptr, nullptr, nullptr,
        0, 0, 0, 0, 0);
}